// Round 4
// baseline (181.371 us; speedup 1.0000x reference)
//
#include <hip/hip_runtime.h>

// ---------------------------------------------------------------------------
// PriceGeometryEncoder on MI355X — round 4.
// 4 dispatches: prep (weights + wqkv transpose + zeros) -> mega (embed + 3
// MLP chains + QKV GEMM, feats never leaves LDS) -> flash attention
// (static-max softmax, NEGM C-operand init, ones-MFMA lsum, setprio) -> head.
// out = (mean_t(o) @ Wo + bo) @ Wout + bout (mean commutes), so attention
// only emits column sums of O.
// ---------------------------------------------------------------------------

typedef __attribute__((ext_vector_type(4)))  float f32x4;
typedef __attribute__((ext_vector_type(16))) float f32x16;
typedef __attribute__((ext_vector_type(4)))  short short4v;
typedef __attribute__((ext_vector_type(8)))  short short8v;

static __device__ __forceinline__ unsigned short f2b(float f) {
    unsigned int u = __builtin_bit_cast(unsigned int, f);
    u += 0x7fffu + ((u >> 16) & 1u);       // round-to-nearest-even
    return (unsigned short)(u >> 16);
}

static __device__ __forceinline__ unsigned int cvtpk_bf16(float a, float b) {
    unsigned int r;
    asm volatile("v_cvt_pk_bf16_f32 %0, %1, %2" : "=v"(r) : "v"(a), "v"(b));
    return r;
}

// ---------------------------------------------------------------------------
// K0: blocks 0..47: Wqkv [128][384] f32 -> [384][128] bf16 via 32x32 tiles.
//     blocks 48+ : small weight transposes + zero pooled/qkmax.
// ---------------------------------------------------------------------------
__global__ __launch_bounds__(256) void prep_kernel(
    const float* Wqkv, const float* Wc1, const float* Wc2, const float* Wv1,
    const float* Wv2, const float* Ws1, const float* Ws2,
    unsigned short* wqkvt, unsigned short* wc1t, unsigned short* wc2t,
    unsigned short* wv1t, unsigned short* wv2t, unsigned short* ws1t,
    unsigned short* ws2t, float* pooled, float* qkmax)
{
    int tid = threadIdx.x;
    if (blockIdx.x < 48) {
        __shared__ float tile[32][33];
        int bidn = blockIdx.x % 12, bidk = blockIdx.x / 12;
        int n0 = bidn * 32, k0 = bidk * 32;
        {
            int r = tid >> 3, cq = tid & 7;
            float4 v = *(const float4*)(Wqkv + (size_t)(k0 + r) * 384 + n0 + cq * 4);
            tile[r][cq*4+0] = v.x; tile[r][cq*4+1] = v.y;
            tile[r][cq*4+2] = v.z; tile[r][cq*4+3] = v.w;
        }
        __syncthreads();
        {
            int nr = tid >> 3, kq = tid & 7;
            union { unsigned short us[4]; short4v v; } pk;
#pragma unroll
            for (int j = 0; j < 4; ++j) pk.us[j] = f2b(tile[kq*4+j][nr]);
            *(short4v*)(wqkvt + (size_t)(n0 + nr) * 128 + k0 + kq * 4) = pk.v;
        }
        return;
    }
    int idx = (blockIdx.x - 48) * 256 + tid;
    if (idx < 8192)  { int n = idx >> 6, kk = idx & 63;  wc1t[idx] = f2b(Wc1[kk*128 + n]); return; }
    idx -= 8192;
    if (idx < 4096)  { int n = idx >> 7, kk = idx & 127; wc2t[idx] = f2b(Wc2[kk*32  + n]); return; }
    idx -= 4096;
    if (idx < 4096)  { int n = idx >> 6, kk = idx & 63;  wv1t[idx] = f2b(Wv1[kk*64  + n]); return; }
    idx -= 4096;
    if (idx < 1024)  { int n = idx >> 6, kk = idx & 63;  wv2t[idx] = f2b(Wv2[kk*16  + n]); return; }
    idx -= 1024;
    if (idx < 4096)  { int n = idx >> 6, kk = idx & 63;  ws1t[idx] = f2b(Ws1[kk*64  + n]); return; }
    idx -= 4096;
    if (idx < 1024)  { int n = idx >> 6, kk = idx & 63;  ws2t[idx] = f2b(Ws2[kk*16  + n]); return; }
    idx -= 1024;
    if (idx < 2048)  { pooled[idx] = 0.f; return; }
    idx -= 2048;
    if (idx < 128)   qkmax[idx] = 0.f;
}

// ---------------------------------------------------------------------------
// Wave-level GEMM: 16 tokens x N, A from LDS [64 rows][256B] (16B-slot XOR
// swizzle, mask 15), B fragments gathered from global bf16 [N][K] (L1/L2).
// ---------------------------------------------------------------------------
template<int N, int K>
static __device__ __forceinline__ void wave_gemm(
    const char* As, const unsigned short* __restrict__ BT,
    int w, int lane, f32x4 (&acc)[N / 16])
{
    int l15 = lane & 15, hi4 = lane >> 4;
#pragma unroll
    for (int nt = 0; nt < N / 16; ++nt)
#pragma unroll
        for (int r = 0; r < 4; ++r) acc[nt][r] = 0.f;
#pragma unroll
    for (int ks = 0; ks < K / 32; ++ks) {
        int slot = ks * 4 + hi4;
        int m = w * 16 + l15;
        short8v af = *(const short8v*)(As + m * 256 + ((slot ^ (m & 15)) << 4));
#pragma unroll
        for (int nt = 0; nt < N / 16; ++nt) {
            int n = nt * 16 + l15;
            short8v bf = *(const short8v*)(BT + (size_t)n * K + slot * 8);
            acc[nt] = __builtin_amdgcn_mfma_f32_16x16x32_bf16(af, bf, acc[nt], 0, 0, 0);
        }
    }
}

// epilogue -> LDS tile (bias + optional ReLU), 16B-slot XOR swizzle mask 15
template<int N, bool RELU>
static __device__ __forceinline__ void epi_lds(
    f32x4 (&acc)[N / 16], const float* __restrict__ bias, int boff,
    char* dst, int ocol, int w, int lane)
{
    int l15 = lane & 15, hi4 = lane >> 4;
#pragma unroll
    for (int nt = 0; nt < N / 16; ++nt) {
        int n = nt * 16 + l15;
        float bv = bias[boff + n];
#pragma unroll
        for (int r = 0; r < 4; ++r) {
            int m = w * 16 + hi4 * 4 + r;
            float v = acc[nt][r] + bv;
            if (RELU) v = fmaxf(v, 0.f);
            int col = ocol + n;
            *(unsigned short*)(dst + m * 256 + (((col >> 3) ^ (m & 15)) << 4) + (col & 7) * 2) = f2b(v);
        }
    }
}

// epilogue for q/k: scale, per-head amax (wave-reduce + atomicMax), bounce
// through the wave's Ht quadrant, coalesced b128 stores to [bh][t][32]
static __device__ __forceinline__ void epi_qk(
    f32x4 (&acc)[8], const float* __restrict__ bias, int boff, float scale,
    unsigned short* __restrict__ og, float* qkmaxp,
    int b, int tp0, int w, int lane, char* bounce)
{
    int l15 = lane & 15, hi4 = lane >> 4;
    float amax[4] = {0.f, 0.f, 0.f, 0.f};
#pragma unroll
    for (int nt = 0; nt < 8; ++nt) {
        int n = nt * 16 + l15;
        float bv = bias[boff + n];
#pragma unroll
        for (int r = 0; r < 4; ++r) {
            int m = w * 16 + hi4 * 4 + r;
            float v = (acc[nt][r] + bv) * scale;
            amax[nt >> 1] = fmaxf(amax[nt >> 1], fabsf(v));
            *(unsigned short*)(bounce + m * 256 + (((n >> 3) ^ (m & 15)) << 4) + (n & 7) * 2) = f2b(v);
        }
    }
#pragma unroll
    for (int g = 0; g < 4; ++g) {
        float mv = amax[g];
        mv = fmaxf(mv, __shfl_xor(mv, 1));  mv = fmaxf(mv, __shfl_xor(mv, 2));
        mv = fmaxf(mv, __shfl_xor(mv, 4));  mv = fmaxf(mv, __shfl_xor(mv, 8));
        mv = fmaxf(mv, __shfl_xor(mv, 16)); mv = fmaxf(mv, __shfl_xor(mv, 32));
        if (lane == 0)
            atomicMax((int*)(qkmaxp + b * 4 + g), __float_as_int(mv));
    }
#pragma unroll
    for (int it = 0; it < 4; ++it) {
        int ch = it * 64 + lane;
        int ml = ch >> 4, c = ch & 15;
        int m = w * 16 + ml;
        short8v vv = *(const short8v*)(bounce + m * 256 + ((c ^ (m & 15)) << 4));
        int h = c >> 2, dq = c & 3;
        *(short8v*)(og + ((size_t)(b * 4 + h) * 2048 + tp0 + m) * 32 + dq * 8) = vv;
    }
}

// ---------------------------------------------------------------------------
// K1: mega — embed + curvature/volatility/sr MLPs + QKV, 64 tokens/block,
// 4 waves x 16 tokens, ONE barrier (wp staging); everything else per-wave.
// feats tile (Ft) never goes to global. q/k -> [bh][t][32]; v -> vT[bh][dh][t].
// ---------------------------------------------------------------------------
__global__ __launch_bounds__(256) void mega_kernel(
    const float* __restrict__ ohlc, const float* __restrict__ Wp, const float* __restrict__ bp,
    const unsigned short* __restrict__ wc1t, const float* __restrict__ bc1,
    const unsigned short* __restrict__ wc2t, const float* __restrict__ bc2,
    const unsigned short* __restrict__ wv1t, const float* __restrict__ bv1,
    const unsigned short* __restrict__ wv2t, const float* __restrict__ bv2,
    const unsigned short* __restrict__ ws1t, const float* __restrict__ bs1,
    const unsigned short* __restrict__ ws2t, const float* __restrict__ bs2,
    const unsigned short* __restrict__ wqkvt, const float* __restrict__ bqkv,
    unsigned short* __restrict__ qg, unsigned short* __restrict__ kg,
    unsigned short* __restrict__ vTg, float* __restrict__ qkmax)
{
    __shared__ float wp[256];
    __shared__ float bpl[64];
    __shared__ char Ft[64 * 256];    // full feats tile [64 tok][128 col] bf16
    __shared__ char Ht[64 * 256];    // hidden tile / epilogue bounce

    int tid = threadIdx.x;
    int m0 = blockIdx.x * 64;
    wp[tid] = Wp[tid];
    if (tid < 64) bpl[tid] = bp[tid];
    __syncthreads();

    {   // embed: e = ohlc @ Wp + bp -> Ft cols 0..63 (per-wave-aligned rows)
        int tok = tid >> 2, jq = tid & 3;
        float4 ov = ((const float4*)ohlc)[m0 + tok];
#pragma unroll
        for (int c = 0; c < 2; ++c) {
            int sl = jq * 2 + c;            // 16B slot 0..7
            union { unsigned short us[8]; short8v v; } pk;
#pragma unroll
            for (int jj = 0; jj < 8; ++jj) {
                int j = sl * 8 + jj;
                float e = bpl[j] + ov.x * wp[j] + ov.y * wp[64 + j]
                                 + ov.z * wp[128 + j] + ov.w * wp[192 + j];
                pk.us[jj] = f2b(e);
            }
            *(short8v*)(Ft + tok * 256 + ((sl ^ (tok & 15)) << 4)) = pk.v;
        }
    }
    // NOTE: no barrier needed — wave w's threads wrote exactly rows 16w..16w+15.

    int lane = tid & 63, w = tid >> 6;
    {
        f32x4 a8[8];
        wave_gemm<128, 64>(Ft, wc1t, w, lane, a8);          // curvature L1
        epi_lds<128, true>(a8, bc1, 0, Ht, 0, w, lane);
    }
    {
        f32x4 a2[2];
        wave_gemm<32, 128>(Ht, wc2t, w, lane, a2);          // curvature L2
        epi_lds<32, false>(a2, bc2, 0, Ft, 64, w, lane);
    }
    {
        f32x4 a4[4];
        wave_gemm<64, 64>(Ft, wv1t, w, lane, a4);           // volatility L1
        epi_lds<64, true>(a4, bv1, 0, Ht, 0, w, lane);
    }
    {
        f32x4 a1[1];
        wave_gemm<16, 64>(Ht, wv2t, w, lane, a1);           // volatility L2
        epi_lds<16, false>(a1, bv2, 0, Ft, 96, w, lane);
    }
    {
        f32x4 a4[4];
        wave_gemm<64, 64>(Ft, ws1t, w, lane, a4);           // sr L1
        epi_lds<64, true>(a4, bs1, 0, Ht, 0, w, lane);
    }
    {
        f32x4 a1[1];
        wave_gemm<16, 64>(Ht, ws2t, w, lane, a1);           // sr L2
        epi_lds<16, false>(a1, bs2, 0, Ft, 112, w, lane);
    }

    // ---- QKV from the completed Ft tile ----
    const float QSCALE = 1.4426950408889634f * 0.17677669529663687f; // log2e/sqrt(32)
    int b = m0 >> 11, tp0 = m0 & 2047;
    {
        f32x4 aq[8];
        wave_gemm<128, 128>(Ft, wqkvt, w, lane, aq);        // Q
        epi_qk(aq, bqkv, 0, QSCALE, qg, qkmax, b, tp0, w, lane, Ht);
    }
    {
        f32x4 ak[8];
        wave_gemm<128, 128>(Ft, wqkvt + 128 * 128, w, lane, ak);   // K
        epi_qk(ak, bqkv, 128, 1.0f, kg, qkmax + 64, b, tp0, w, lane, Ht);
    }
    {
        f32x4 av[8];
        wave_gemm<128, 128>(Ft, wqkvt + 2 * 128 * 128, w, lane, av); // V
        int l15 = lane & 15, hi4 = lane >> 4;
#pragma unroll
        for (int nt = 0; nt < 8; ++nt) {
            int n = nt * 16 + l15;
            float bv = bqkv[256 + n];
            int h = n >> 5, dh = n & 31;
            uint2 pk;
            pk.x = cvtpk_bf16(av[nt][0] + bv, av[nt][1] + bv);
            pk.y = cvtpk_bf16(av[nt][2] + bv, av[nt][3] + bv);
            int t = tp0 + w * 16 + hi4 * 4;
            *(uint2*)(vTg + ((size_t)(b * 4 + h) * 32 + dh) * 2048 + t) = pk;
        }
    }
}

// ---------------------------------------------------------------------------
// K2: flash attention. bh = bid&63 (XCD L2 locality). K register-double-
// buffered from global; V staged reg->LDS 4-buffer ring; one raw s_barrier +
// lgkmcnt(0) per tile. Static-max softmax: C-init = NEGM (persistent regs,
// no movs); lsum via ones-MFMA (lacc) — no VALU adds, no final shfl.
// ---------------------------------------------------------------------------
__global__ __launch_bounds__(256) void attn_kernel(
    const unsigned short* __restrict__ qg, const unsigned short* __restrict__ kg,
    const unsigned short* __restrict__ vTg, const float* __restrict__ qkmax,
    float* __restrict__ pooled)
{
    __shared__ short8v VsBuf[4 * 256];       // 4 x 4 KiB V tiles
    char* Vs = (char*)VsBuf;

    int tid = threadIdx.x, bid = blockIdx.x;
    int bh = bid & 63, qb = bid >> 6;
    int b = bh >> 2;
    int lane = tid & 63, w = tid >> 6;
    int l31 = lane & 31, hi = lane >> 5;
    int q0 = qb * 128 + w * 32;

    const unsigned short* qrow = qg + ((size_t)bh * 2048 + q0 + l31) * 32;
    short8v Qf0 = *(const short8v*)(qrow + hi * 8);        // kd 0..15
    short8v Qf1 = *(const short8v*)(qrow + 16 + hi * 8);   // kd 16..31

    float negM0 = -(32.0f * qkmax[bh] * qkmax[64 + bh]);
    f32x16 NEGM;
#pragma unroll
    for (int r = 0; r < 16; ++r) NEGM[r] = negM0;

    f32x16 accO, lacc;
#pragma unroll
    for (int r = 0; r < 16; ++r) { accO[r] = 0.f; lacc[r] = 0.f; }

    short8v ONES;
    {
        union { unsigned short us[8]; short8v v; } u;
#pragma unroll
        for (int j = 0; j < 8; ++j) u.us[j] = 0x3F80;      // bf16 1.0
        ONES = u.v;
    }

    // K per-lane base: row l31 (+32 for sub1), 16B col hi*16 (+32 for kd>=16)
    const char* kp = (const char*)(kg + (size_t)bh * 2048 * 32) + (size_t)l31 * 64 + hi * 16;
    // V per-lane: dh = w*8 + (lane>>3); phys slot (lane&7) holds logical slot^(dh&7)
    int vdh = w * 8 + (lane >> 3);
    const char* vp = (const char*)(vTg + ((size_t)bh * 32 + vdh) * 2048) +
                     (((lane & 7) ^ (vdh & 7)) << 4);
    int vdst = (w * 64 + lane) * 16;         // linear LDS dest within buffer
    int voff[4];                              // hoisted V read addrs (j = sub*2+c2)
#pragma unroll
    for (int j = 0; j < 4; ++j)
        voff[j] = l31 * 128 + (((2 * j + hi) ^ (l31 & 7)) << 4);

    auto step = [&](int t, short8v (&kC)[4], short8v& vC,
                    short8v (&kN)[4], short8v& vN, char* bufp) {
        if (t < 31) {
            const char* p = kp + (size_t)(t + 1) * 4096;
            kN[0] = *(const short8v*)(p);
            kN[1] = *(const short8v*)(p + 32);
            kN[2] = *(const short8v*)(p + 2048);
            kN[3] = *(const short8v*)(p + 2080);
            vN = *(const short8v*)(vp + (size_t)(t + 1) * 128);
        }
        *(short8v*)(bufp + vdst) = vC;       // compiler waits vmcnt for vC
        asm volatile("s_waitcnt lgkmcnt(0)" ::: "memory");
        __builtin_amdgcn_s_barrier();
        asm volatile("" ::: "memory");
        __builtin_amdgcn_s_setprio(1);
#pragma unroll
        for (int sub = 0; sub < 2; ++sub) {
            f32x16 s = __builtin_amdgcn_mfma_f32_32x32x16_bf16(kC[sub * 2 + 0], Qf0, NEGM, 0, 0, 0);
            s = __builtin_amdgcn_mfma_f32_32x32x16_bf16(kC[sub * 2 + 1], Qf1, s, 0, 0, 0);
            float p_[16];
#pragma unroll
            for (int r = 0; r < 16; ++r) p_[r] = __builtin_amdgcn_exp2f(s[r]);
#pragma unroll
            for (int c2 = 0; c2 < 2; ++c2) {
                unsigned int wa = cvtpk_bf16(p_[c2 * 8 + 0], p_[c2 * 8 + 1]);
                unsigned int wb = cvtpk_bf16(p_[c2 * 8 + 2], p_[c2 * 8 + 3]);
                unsigned int wc = cvtpk_bf16(p_[c2 * 8 + 4], p_[c2 * 8 + 5]);
                unsigned int wd = cvtpk_bf16(p_[c2 * 8 + 6], p_[c2 * 8 + 7]);
                asm volatile("v_permlane32_swap_b32 %0, %1" : "+v"(wa), "+v"(wc));
                asm volatile("v_permlane32_swap_b32 %0, %1" : "+v"(wb), "+v"(wd));
                union { unsigned int u[4]; short8v v; } pf;
                pf.u[0] = wa; pf.u[1] = wb; pf.u[2] = wc; pf.u[3] = wd;

                lacc = __builtin_amdgcn_mfma_f32_32x32x16_bf16(ONES, pf.v, lacc, 0, 0, 0);
                short8v vf = *(const short8v*)(bufp + voff[sub * 2 + c2]);
                accO = __builtin_amdgcn_mfma_f32_32x32x16_bf16(vf, pf.v, accO, 0, 0, 0);
            }
        }
        __builtin_amdgcn_s_setprio(0);
    };

    short8v kE[4], kO[4], vE, vO;
    {
        kE[0] = *(const short8v*)(kp);
        kE[1] = *(const short8v*)(kp + 32);
        kE[2] = *(const short8v*)(kp + 2048);
        kE[3] = *(const short8v*)(kp + 2080);
        vE = *(const short8v*)(vp);
    }
#pragma unroll 1
    for (int g = 0; g < 8; ++g) {
        int t0 = g * 4;
        step(t0 + 0, kE, vE, kO, vO, Vs + 0 * 4096);
        step(t0 + 1, kO, vO, kE, vE, Vs + 1 * 4096);
        step(t0 + 2, kE, vE, kO, vO, Vs + 2 * 4096);
        step(t0 + 3, kO, vO, kE, vE, Vs + 3 * 4096);
    }

    // lsum per q = any row of lacc (ones-MFMA summed all keys already)
    float inv = 1.0f / (lacc[0] + 1e-30f);
#pragma unroll
    for (int r = 0; r < 16; ++r) {
        float v = accO[r] * inv;
        v += __shfl_xor(v, 1); v += __shfl_xor(v, 2); v += __shfl_xor(v, 4);
        v += __shfl_xor(v, 8); v += __shfl_xor(v, 16);
        if (l31 == 0) {
            int dh = (r & 3) + 8 * (r >> 2) + 4 * hi;
            atomicAdd(pooled + b * 128 + (bh & 3) * 32 + dh, v);
        }
    }
}

// ---------------------------------------------------------------------------
// K3: out[b] = (pooled[b]/2048 @ Wo + bo) @ Wout + bout   (f32, tiny)
// ---------------------------------------------------------------------------
__global__ __launch_bounds__(256) void head_kernel(
    const float* __restrict__ pooled, const float* __restrict__ Wo,
    const float* __restrict__ bo, const float* __restrict__ Wout,
    const float* __restrict__ bout, float* __restrict__ out)
{
    int bq = blockIdx.x, tid = threadIdx.x;
    __shared__ float pl[128], mid[128];
    if (tid < 128) pl[tid] = pooled[bq * 128 + tid] * (1.f / 2048.f);
    __syncthreads();
    if (tid < 128) {
        float s = bo[tid];
#pragma unroll 4
        for (int c = 0; c < 128; ++c) s += pl[c] * Wo[c * 128 + tid];
        mid[tid] = s;
    }
    __syncthreads();
    for (int j = tid; j < 512; j += 256) {
        float s = bout[j];
#pragma unroll 4
        for (int i = 0; i < 128; ++i) s += mid[i] * Wout[i * 512 + j];
        out[bq * 512 + j] = s;
    }
}

// ---------------------------------------------------------------------------
extern "C" void kernel_launch(void* const* d_in, const int* in_sizes, int n_in,
                              void* d_out, int out_size, void* d_ws, size_t ws_size,
                              hipStream_t stream) {
    (void)in_sizes; (void)n_in; (void)out_size; (void)ws_size;
    const float* ohlc = (const float*)d_in[0];
    const float* Wp   = (const float*)d_in[1];  const float* bp   = (const float*)d_in[2];
    const float* Wc1  = (const float*)d_in[3];  const float* bc1  = (const float*)d_in[4];
    const float* Wc2  = (const float*)d_in[5];  const float* bc2  = (const float*)d_in[6];
    const float* Wv1  = (const float*)d_in[7];  const float* bv1  = (const float*)d_in[8];
    const float* Wv2  = (const float*)d_in[9];  const float* bv2  = (const float*)d_in[10];
    const float* Ws1  = (const float*)d_in[11]; const float* bs1  = (const float*)d_in[12];
    const float* Ws2  = (const float*)d_in[13]; const float* bs2  = (const float*)d_in[14];
    const float* Wqkv = (const float*)d_in[15]; const float* bqkv = (const float*)d_in[16];
    const float* Wo   = (const float*)d_in[17]; const float* bo   = (const float*)d_in[18];
    const float* Wout = (const float*)d_in[19]; const float* bout = (const float*)d_in[20];
    float* out = (float*)d_out;
    char* ws = (char*)d_ws;

    const size_t MB8 = 8388608;
    unsigned short* qg    = (unsigned short*)(ws);
    unsigned short* kg    = (unsigned short*)(ws + 1 * MB8);
    unsigned short* vTg   = (unsigned short*)(ws + 2 * MB8);
    float*          pooled = (float*)(ws + 3 * MB8);
    float*          qkmax  = (float*)(ws + 3 * MB8 + 8192);
    unsigned short* wc1t  = (unsigned short*)(ws + 3 * MB8 + 8192 + 512);
    unsigned short* wc2t  = wc1t + 8192;
    unsigned short* wv1t  = wc2t + 4096;
    unsigned short* wv2t  = wv1t + 4096;
    unsigned short* ws1t  = wv2t + 1024;
    unsigned short* ws2t  = ws1t + 4096;
    unsigned short* wqkvt = ws2t + 1024;

    prep_kernel<<<145, 256, 0, stream>>>(Wqkv, Wc1, Wc2, Wv1, Wv2, Ws1, Ws2,
                                         wqkvt, wc1t, wc2t, wv1t, wv2t, ws1t, ws2t,
                                         pooled, qkmax);
    mega_kernel<<<512, 256, 0, stream>>>(ohlc, Wp, bp, wc1t, bc1, wc2t, bc2,
                                         wv1t, bv1, wv2t, bv2, ws1t, bs1, ws2t, bs2,
                                         wqkvt, bqkv, qg, kg, vTg, qkmax);
    attn_kernel<<<1024, 256, 0, stream>>>(qg, kg, vTg, qkmax, pooled);
    head_kernel<<<16, 256, 0, stream>>>(pooled, Wo, bo, Wout, bout, out);
}